// Round 5
// baseline (434.923 us; speedup 1.0000x reference)
//
#include <hip/hip_runtime.h>
#include <math.h>
#include <float.h>

#define NG 64
#define GDIM 128

typedef short bf16x8 __attribute__((ext_vector_type(8)));
typedef float f32x4 __attribute__((ext_vector_type(4)));

__device__ inline unsigned short f2b(float f) {
    unsigned u = __builtin_bit_cast(unsigned, f);
    unsigned r = u + 0x7FFFu + ((u >> 16) & 1u);
    return (unsigned short)(r >> 16);
}
__device__ inline float b2f(unsigned short b) {
    unsigned u = ((unsigned)b) << 16;
    return __builtin_bit_cast(float, u);
}

// ---------------- CSR build ----------------
__global__ void zero_int_kernel(int* p, int n) {
    int i = blockIdx.x * blockDim.x + threadIdx.x;
    if (i < n) p[i] = 0;
}
__global__ void count_kernel(const int* __restrict__ col, int* cnt, int E) {
    int i = blockIdx.x * blockDim.x + threadIdx.x;
    if (i < E) atomicAdd(&cnt[col[i]], 1);
}
__global__ void dinv_kernel(const int* __restrict__ cnt, float* dinv, int n) {
    int i = blockIdx.x * blockDim.x + threadIdx.x;
    if (i < n) dinv[i] = rsqrtf((float)cnt[i] + 1.0f);
}

#define SCAN_BS 256
__global__ void scan_partial_kernel(const int* __restrict__ cnt, int* __restrict__ bsum, int n) {
    __shared__ int red[SCAN_BS];
    int i = blockIdx.x * SCAN_BS + threadIdx.x;
    red[threadIdx.x] = (i < n) ? cnt[i] : 0;
    __syncthreads();
    #pragma unroll
    for (int off = SCAN_BS / 2; off > 0; off >>= 1) {
        if (threadIdx.x < off) red[threadIdx.x] += red[threadIdx.x + off];
        __syncthreads();
    }
    if (threadIdx.x == 0) bsum[blockIdx.x] = red[0];
}
__global__ __launch_bounds__(SCAN_BS) void scan_bsum_kernel(int* bsum, int nb) {
    __shared__ int buf[SCAN_BS];
    int t = threadIdx.x;
    buf[t] = (t < nb) ? bsum[t] : 0;
    __syncthreads();
    #pragma unroll
    for (int off = 1; off < SCAN_BS; off <<= 1) {
        int v = (t >= off) ? buf[t - off] : 0;
        __syncthreads();
        buf[t] += v;
        __syncthreads();
    }
    int ex = (t == 0) ? 0 : buf[t - 1];
    if (t < nb) bsum[t] = ex;
}
__global__ void scan_final_kernel(const int* __restrict__ cnt, const int* __restrict__ bsum,
                                  int* __restrict__ start, int n) {
    __shared__ int buf[SCAN_BS];
    int b = blockIdx.x, t = threadIdx.x;
    int i = b * SCAN_BS + t;
    buf[t] = (i < n) ? cnt[i] : 0;
    __syncthreads();
    #pragma unroll
    for (int off = 1; off < SCAN_BS; off <<= 1) {
        int v = (t >= off) ? buf[t - off] : 0;
        __syncthreads();
        buf[t] += v;
        __syncthreads();
    }
    if (i < n) start[i + 1] = bsum[b] + buf[t];
    if (i == 0) start[0] = 0;
}

__global__ void copy_int_kernel(const int* __restrict__ a, int* b, int n) {
    int i = blockIdx.x * blockDim.x + threadIdx.x;
    if (i < n) b[i] = a[i];
}
__global__ void fill_kernel(const int* __restrict__ row, const int* __restrict__ col,
                            int* cursor, int* __restrict__ esrc, int E) {
    int e = blockIdx.x * blockDim.x + threadIdx.x;
    if (e >= E) return;
    int c = col[e];
    int p = atomicAdd(&cursor[c], 1);
    esrc[p] = row[e];
}

// ---------------- glob init ----------------
__global__ void glob_tile_kernel(const float* __restrict__ gi, float* glob) {
    glob[blockIdx.x * GDIM + threadIdx.x] = gi[threadIdx.x];
}

// ---------------- gn = glob @ Wgn + bgn ----------------
template <int DOUT>
__global__ __launch_bounds__(1024) void gn_kernel(const float* __restrict__ glob,
                                                  const float* __restrict__ Wgn,
                                                  const float* __restrict__ bgn,
                                                  float* __restrict__ gn) {
    constexpr int Q = 1024 / DOUT;
    constexpr int KS = GDIM / Q;
    __shared__ float gr[GDIM];
    __shared__ float red[Q][DOUT];
    int g = blockIdx.x, tid = threadIdx.x;
    if (tid < GDIM) gr[tid] = glob[g * GDIM + tid];
    __syncthreads();
    int j = tid % DOUT, q = tid / DOUT;
    float s = 0.f;
    #pragma unroll
    for (int k = 0; k < KS; ++k) {
        int kk = q * KS + k;
        s = fmaf(gr[kk], Wgn[(size_t)kk * DOUT + j], s);
    }
    red[q][j] = s;
    __syncthreads();
    if (q == 0) {
        float r = s + bgn[j];
        #pragma unroll
        for (int t = 1; t < Q; ++t) r += red[t][j];
        gn[(size_t)g * DOUT + j] = r;
    }
}

// ---------------- glob update ----------------
__global__ __launch_bounds__(512) void glob_update_kernel(
    const float* __restrict__ glob, const float* __restrict__ Wgg,
    const float* __restrict__ bgg, const float* __restrict__ parts,
    const float* __restrict__ Wng, const float* __restrict__ bng,
    float* __restrict__ out) {
    __shared__ float gr[GDIM];
    __shared__ float pr[256];
    __shared__ float red[4][GDIM];
    int g = blockIdx.x, tid = threadIdx.x;
    if (tid < GDIM) gr[tid] = glob[g * GDIM + tid];
    else if (tid < GDIM + 256) pr[tid - GDIM] = parts[(size_t)g * 256 + (tid - GDIM)];
    __syncthreads();
    int j = tid & 127, q = tid >> 7;
    float s = 0.f;
    #pragma unroll
    for (int k = 0; k < 32; ++k) {
        int kk = q * 32 + k;
        s = fmaf(gr[kk], Wgg[(size_t)kk * GDIM + j], s);
    }
    #pragma unroll
    for (int k = 0; k < 64; ++k) {
        int kk = q * 64 + k;
        s = fmaf(pr[kk], Wng[(size_t)kk * GDIM + j], s);
    }
    red[q][j] = s;
    __syncthreads();
    if (q == 0) {
        out[(size_t)g * GDIM + j] =
            red[0][j] + red[1][j] + red[2][j] + red[3][j] + bgg[j] + bng[j];
    }
}

// ---------------- x -> bf16 ----------------
__global__ void cvtx_kernel(const float* __restrict__ x, unsigned short* __restrict__ xb,
                            int total4) {
    int i = blockIdx.x * blockDim.x + threadIdx.x;
    if (i >= total4) return;
    float4 v = ((const float4*)x)[i];
    ushort4 o;
    o.x = f2b(v.x); o.y = f2b(v.y); o.z = f2b(v.z); o.w = f2b(v.w);
    ((ushort4*)xb)[i] = o;
}

// ---------------- W [K][DOUT] fp32 -> Wt [DOUT][K] bf16 ----------------
__global__ void wtrans_kernel(const float* __restrict__ W, unsigned short* __restrict__ Wt,
                              int K, int DOUT) {
    __shared__ float t[32][33];
    int k0 = blockIdx.x * 32, c0 = blockIdx.y * 32;
    int tx = threadIdx.x, ty = threadIdx.y;
    #pragma unroll
    for (int i = 0; i < 4; ++i)
        t[ty + i * 8][tx] = W[(size_t)(k0 + ty + i * 8) * DOUT + c0 + tx];
    __syncthreads();
    #pragma unroll
    for (int i = 0; i < 4; ++i)
        Wt[(size_t)(c0 + ty + i * 8) * K + k0 + tx] = f2b(t[tx][ty + i * 8]);
}

// ---------------- MFMA GEMM: Cb(bf16) = relu?(A) @ Wt^T + bias + gn[ga] ----------------
template <int BM, int BN>
__global__ __launch_bounds__(256) void mfma_gemm_kernel(
    const unsigned short* __restrict__ A, const unsigned short* __restrict__ Wt,
    const float* __restrict__ bias, const float* __restrict__ gn,
    const int* __restrict__ ga, unsigned short* __restrict__ Cb,
    int N, int K, int relu)
{
    __shared__ unsigned short Alds[BM * 32];
    __shared__ unsigned short Blds[BN * 32];
    int tid = threadIdx.x;
    int lane = tid & 63, wave = tid >> 6;
    constexpr int WN = BN / 64;
    int wm = wave / WN, wn = wave % WN;
    int row0 = blockIdx.x * BM;
    f32x4 acc[4][4];
    #pragma unroll
    for (int i = 0; i < 4; ++i)
        #pragma unroll
        for (int j = 0; j < 4; ++j) acc[i][j] = (f32x4){0.f, 0.f, 0.f, 0.f};

    for (int k0 = 0; k0 < K; k0 += 32) {
        #pragma unroll
        for (int i = 0; i < BM / 64; ++i) {
            int s = tid + i * 256;
            int mf = s >> 6, kg = (s >> 4) & 3, r = s & 15;
            int grow = row0 + mf * 16 + r;
            int4 v = (int4){0, 0, 0, 0};
            if (grow < N) v = *(const int4*)(A + (size_t)grow * K + k0 + kg * 8);
            if (relu) {
                unsigned short* p = (unsigned short*)&v;
                #pragma unroll
                for (int q = 0; q < 8; ++q) p[q] = (p[q] & 0x8000) ? (unsigned short)0 : p[q];
            }
            *(int4*)(Alds + (size_t)s * 8) = v;
        }
        #pragma unroll
        for (int i = 0; i < BN / 64; ++i) {
            int s = tid + i * 256;
            int nf = s >> 6, kg = (s >> 4) & 3, c = s & 15;
            int col = nf * 16 + c;
            int4 v = *(const int4*)(Wt + (size_t)col * K + k0 + kg * 8);
            *(int4*)(Blds + (size_t)s * 8) = v;
        }
        __syncthreads();
        bf16x8 af[4], bfr[4];
        #pragma unroll
        for (int m = 0; m < 4; ++m)
            af[m] = *(const bf16x8*)(Alds + (size_t)(((wm * 4 + m) * 4 + (lane >> 4)) * 16 + (lane & 15)) * 8);
        #pragma unroll
        for (int nn = 0; nn < 4; ++nn)
            bfr[nn] = *(const bf16x8*)(Blds + (size_t)(((wn * 4 + nn) * 4 + (lane >> 4)) * 16 + (lane & 15)) * 8);
        #pragma unroll
        for (int m = 0; m < 4; ++m)
            #pragma unroll
            for (int nn = 0; nn < 4; ++nn)
                acc[m][nn] = __builtin_amdgcn_mfma_f32_16x16x32_bf16(af[m], bfr[nn], acc[m][nn], 0, 0, 0);
        __syncthreads();
    }

    int cbase = lane & 15;
    float bb[4];
    #pragma unroll
    for (int nn = 0; nn < 4; ++nn) bb[nn] = bias[(wn * 4 + nn) * 16 + cbase];
    #pragma unroll
    for (int m = 0; m < 4; ++m) {
        int rb = row0 + (wm * 4 + m) * 16 + (lane >> 4) * 4;
        #pragma unroll
        for (int reg = 0; reg < 4; ++reg) {
            int r = rb + reg;
            if (r < N) {
                int g = ga[r];
                const float* gnr = gn + (size_t)g * BN;
                #pragma unroll
                for (int nn = 0; nn < 4; ++nn) {
                    int col = (wn * 4 + nn) * 16 + cbase;
                    Cb[(size_t)r * BN + col] = f2b(acc[m][nn][reg] + bb[nn] + gnr[col]);
                }
            }
        }
    }
}

// ---------------- gather 256-wide: one wave per node, bf16 in, bf16 out ----------------
__global__ void gather256_kernel(const unsigned short* __restrict__ tmp,
                                 unsigned short* __restrict__ outp,
                                 const int* __restrict__ start, const int* __restrict__ esrc,
                                 const float* __restrict__ dinv, int n) {
    int gt = blockIdx.x * blockDim.x + threadIdx.x;
    int node = gt >> 6;
    if (node >= n) return;
    int lane = gt & 63;
    float dc = dinv[node];
    ushort4 v = ((const ushort4*)(tmp + (size_t)node * 256))[lane];
    float s0 = dc * dc;
    float a0 = s0 * b2f(v.x), a1 = s0 * b2f(v.y), a2 = s0 * b2f(v.z), a3 = s0 * b2f(v.w);
    int a = start[node], b = start[node + 1];
    for (int j = a; j < b; ++j) {
        int r = esrc[j];
        float nrm = dc * dinv[r];
        ushort4 u = ((const ushort4*)(tmp + (size_t)r * 256))[lane];
        a0 = fmaf(nrm, b2f(u.x), a0);
        a1 = fmaf(nrm, b2f(u.y), a1);
        a2 = fmaf(nrm, b2f(u.z), a2);
        a3 = fmaf(nrm, b2f(u.w), a3);
    }
    ushort4 o;
    o.x = f2b(a0); o.y = f2b(a1); o.z = f2b(a2); o.w = f2b(a3);
    ((ushort4*)(outp + (size_t)node * 256))[lane] = o;
}

// ---------------- gather 64-wide + sigmoid: 16 lanes/node, bf16 in, fp32 out ----------------
__global__ void gather64_kernel(const unsigned short* __restrict__ tmp,
                                float* __restrict__ outp,
                                const int* __restrict__ start, const int* __restrict__ esrc,
                                const float* __restrict__ dinv, int n) {
    int gt = blockIdx.x * blockDim.x + threadIdx.x;
    int node = gt >> 4;
    if (node >= n) return;
    int lane = gt & 15;
    float dc = dinv[node];
    ushort4 v = ((const ushort4*)(tmp + (size_t)node * 64))[lane];
    float s0 = dc * dc;
    float a0 = s0 * b2f(v.x), a1 = s0 * b2f(v.y), a2 = s0 * b2f(v.z), a3 = s0 * b2f(v.w);
    int a = start[node], b = start[node + 1];
    for (int j = a; j < b; ++j) {
        int r = esrc[j];
        float nrm = dc * dinv[r];
        ushort4 u = ((const ushort4*)(tmp + (size_t)r * 64))[lane];
        a0 = fmaf(nrm, b2f(u.x), a0);
        a1 = fmaf(nrm, b2f(u.y), a1);
        a2 = fmaf(nrm, b2f(u.z), a2);
        a3 = fmaf(nrm, b2f(u.w), a3);
    }
    float4 o;
    o.x = 1.0f / (1.0f + expf(-a0));
    o.y = 1.0f / (1.0f + expf(-a1));
    o.z = 1.0f / (1.0f + expf(-a2));
    o.w = 1.0f / (1.0f + expf(-a3));
    ((float4*)(outp + (size_t)node * 64))[lane] = o;
}

// ---------------- per-graph max on bf16 h ----------------
__global__ void parts_partial_kernel(const unsigned short* __restrict__ h,
                                     const int* __restrict__ ga,
                                     float* __restrict__ pp, int n, int dout) {
    int g = blockIdx.x, ch = blockIdx.y, nch = gridDim.y;
    int lo = 0, hi = n;
    while (lo < hi) { int m = (lo + hi) >> 1; if (ga[m] < g) lo = m + 1; else hi = m; }
    int s = lo;
    lo = s; hi = n;
    while (lo < hi) { int m = (lo + hi) >> 1; if (ga[m] <= g) lo = m + 1; else hi = m; }
    int epos = lo;
    int cnt = epos - s;
    int per = (cnt + nch - 1) / nch;
    int a = s + ch * per;
    int b = min(epos, a + per);
    for (int j = threadIdx.x; j < dout; j += blockDim.x) {
        float m = -INFINITY;
        for (int i = a; i < b; ++i) m = fmaxf(m, b2f(h[(size_t)i * dout + j]));
        pp[((size_t)g * nch + ch) * dout + j] = m;
    }
}
__global__ void parts_reduce_kernel(const float* __restrict__ pp, float* __restrict__ parts,
                                    int dout, int nch) {
    int g = blockIdx.x, j = threadIdx.x;
    float m = -INFINITY;
    for (int c = 0; c < nch; ++c) m = fmaxf(m, pp[((size_t)g * nch + c) * dout + j]);
    parts[g * dout + j] = m;
}

extern "C" void kernel_launch(void* const* d_in, const int* in_sizes, int n_in,
                              void* d_out, int out_size, void* d_ws, size_t ws_size,
                              hipStream_t stream) {
    const float* x         = (const float*)d_in[0];
    const int*   ei        = (const int*)d_in[1];
    const int*   ga        = (const int*)d_in[2];
    const float* glob_init = (const float*)d_in[3];

    const int n = in_sizes[0] / 128;   // 50000
    const int E = in_sizes[1] / 2;     // 400000
    const int* row = ei;               // sources
    const int* col = ei + E;           // targets

    float* ws = (float*)d_ws;
    size_t off = 0;
    auto alloc = [&](size_t cnt) { float* p = ws + off; off += cnt; return p; };
    unsigned short* tb    = (unsigned short*)alloc((size_t)n * 128);  // bf16 tmp [N][256]
    unsigned short* hb    = (unsigned short*)alloc((size_t)n * 128);  // bf16 h   [N][256]
    unsigned short* xb    = (unsigned short*)alloc((size_t)n * 64);   // bf16 x   [N][128]
    unsigned short* Wt    = (unsigned short*)alloc((size_t)32768);
    float* dinv  = alloc((size_t)n);
    float* gnbuf = alloc((size_t)NG * 256);
    float* pp    = alloc((size_t)NG * 16 * 256);
    float* parts = alloc((size_t)NG * 256);
    float* globA = alloc((size_t)NG * GDIM);
    float* globB = alloc((size_t)NG * GDIM);
    int* cnt    = (int*)alloc((size_t)n);
    int* startA = (int*)alloc((size_t)n + 1);
    int* cursor = (int*)alloc((size_t)n);
    int* esrc   = (int*)alloc((size_t)E);
    int* bsum   = (int*)alloc((size_t)SCAN_BS);
    (void)ws_size; (void)n_in; (void)out_size;

    const int nb = (n + SCAN_BS - 1) / SCAN_BS;

    // ---- CSR build ----
    zero_int_kernel<<<(n + 255) / 256, 256, 0, stream>>>(cnt, n);
    count_kernel<<<(E + 255) / 256, 256, 0, stream>>>(col, cnt, E);
    dinv_kernel<<<(n + 255) / 256, 256, 0, stream>>>(cnt, dinv, n);
    scan_partial_kernel<<<nb, SCAN_BS, 0, stream>>>(cnt, bsum, n);
    scan_bsum_kernel<<<1, SCAN_BS, 0, stream>>>(bsum, nb);
    scan_final_kernel<<<nb, SCAN_BS, 0, stream>>>(cnt, bsum, startA, n);
    copy_int_kernel<<<(n + 255) / 256, 256, 0, stream>>>(startA, cursor, n);
    fill_kernel<<<(E + 255) / 256, 256, 0, stream>>>(row, col, cursor, esrc, E);

    glob_tile_kernel<<<NG, GDIM, 0, stream>>>(glob_init, globA);
    cvtx_kernel<<<((size_t)n * 32 + 255) / 256, 256, 0, stream>>>(x, xb, n * 32);

    float* gcur = globA;
    float* gnext = globB;
    int K = 128;
    for (int li = 0; li < 3; ++li) {
        const float* Wnn = (const float*)d_in[4 + li * 8 + 0];
        const float* bnn = (const float*)d_in[4 + li * 8 + 1];
        const float* Wgn = (const float*)d_in[4 + li * 8 + 2];
        const float* bgn = (const float*)d_in[4 + li * 8 + 3];
        const float* Wgg = (const float*)d_in[4 + li * 8 + 4];
        const float* bgg = (const float*)d_in[4 + li * 8 + 5];
        const float* Wng = (const float*)d_in[4 + li * 8 + 6];
        const float* bng = (const float*)d_in[4 + li * 8 + 7];
        const int dout = (li == 2) ? 64 : 256;

        dim3 wtg(K / 32, dout / 32);
        wtrans_kernel<<<wtg, dim3(32, 8), 0, stream>>>(Wnn, Wt, K, dout);
        if (dout == 256)
            gn_kernel<256><<<NG, 1024, 0, stream>>>(gcur, Wgn, bgn, gnbuf);
        else
            gn_kernel<64><<<NG, 1024, 0, stream>>>(gcur, Wgn, bgn, gnbuf);

        if (li == 0) {
            mfma_gemm_kernel<64, 256><<<(n + 63) / 64, 256, 0, stream>>>(
                xb, Wt, bnn, gnbuf, ga, tb, n, 128, 0);
        } else if (li == 1) {
            mfma_gemm_kernel<64, 256><<<(n + 63) / 64, 256, 0, stream>>>(
                hb, Wt, bnn, gnbuf, ga, tb, n, 256, 1);
        } else {
            mfma_gemm_kernel<256, 64><<<(n + 255) / 256, 256, 0, stream>>>(
                hb, Wt, bnn, gnbuf, ga, tb, n, 256, 1);
        }

        if (li < 2) {
            gather256_kernel<<<((size_t)n * 64 + 255) / 256, 256, 0, stream>>>(
                tb, hb, startA, esrc, dinv, n);
            dim3 pgrid(NG, 16);
            parts_partial_kernel<<<pgrid, 256, 0, stream>>>(hb, ga, pp, n, dout);
            parts_reduce_kernel<<<NG, dout, 0, stream>>>(pp, parts, dout, 16);
            glob_update_kernel<<<NG, 512, 0, stream>>>(gcur, Wgg, bgg, parts, Wng, bng, gnext);
            float* t = gcur; gcur = gnext; gnext = t;
        } else {
            gather64_kernel<<<((size_t)n * 16 + 255) / 256, 256, 0, stream>>>(
                tb, (float*)d_out, startA, esrc, dinv, n);
        }
        K = dout;
    }
}

// Round 6
// 307.469 us; speedup vs baseline: 1.4145x; 1.4145x over previous
//
#include <hip/hip_runtime.h>
#include <math.h>
#include <float.h>

#define NG 64
#define GDIM 128

typedef short bf16x8 __attribute__((ext_vector_type(8)));
typedef float f32x4 __attribute__((ext_vector_type(4)));

__device__ inline unsigned short f2b(float f) {
    unsigned u = __builtin_bit_cast(unsigned, f);
    unsigned r = u + 0x7FFFu + ((u >> 16) & 1u);
    return (unsigned short)(r >> 16);
}
__device__ inline float b2f(unsigned short b) {
    unsigned u = ((unsigned)b) << 16;
    return __builtin_bit_cast(float, u);
}

// ---------------- CSR build ----------------
__global__ void zero_int_kernel(int* p, int n) {
    int i = blockIdx.x * blockDim.x + threadIdx.x;
    if (i < n) p[i] = 0;
}
__global__ void count_kernel(const int* __restrict__ col, int* cnt, int E) {
    int i = blockIdx.x * blockDim.x + threadIdx.x;
    if (i < E) atomicAdd(&cnt[col[i]], 1);
}
__global__ void dinv_kernel(const int* __restrict__ cnt, float* dinv, int n) {
    int i = blockIdx.x * blockDim.x + threadIdx.x;
    if (i < n) dinv[i] = rsqrtf((float)cnt[i] + 1.0f);
}

#define SCAN_BS 256
__global__ void scan_partial_kernel(const int* __restrict__ cnt, int* __restrict__ bsum, int n) {
    __shared__ int red[SCAN_BS];
    int i = blockIdx.x * SCAN_BS + threadIdx.x;
    red[threadIdx.x] = (i < n) ? cnt[i] : 0;
    __syncthreads();
    #pragma unroll
    for (int off = SCAN_BS / 2; off > 0; off >>= 1) {
        if (threadIdx.x < off) red[threadIdx.x] += red[threadIdx.x + off];
        __syncthreads();
    }
    if (threadIdx.x == 0) bsum[blockIdx.x] = red[0];
}
__global__ __launch_bounds__(SCAN_BS) void scan_bsum_kernel(int* bsum, int nb) {
    __shared__ int buf[SCAN_BS];
    int t = threadIdx.x;
    buf[t] = (t < nb) ? bsum[t] : 0;
    __syncthreads();
    #pragma unroll
    for (int off = 1; off < SCAN_BS; off <<= 1) {
        int v = (t >= off) ? buf[t - off] : 0;
        __syncthreads();
        buf[t] += v;
        __syncthreads();
    }
    int ex = (t == 0) ? 0 : buf[t - 1];
    if (t < nb) bsum[t] = ex;
}
__global__ void scan_final_kernel(const int* __restrict__ cnt, const int* __restrict__ bsum,
                                  int* __restrict__ start, int n) {
    __shared__ int buf[SCAN_BS];
    int b = blockIdx.x, t = threadIdx.x;
    int i = b * SCAN_BS + t;
    buf[t] = (i < n) ? cnt[i] : 0;
    __syncthreads();
    #pragma unroll
    for (int off = 1; off < SCAN_BS; off <<= 1) {
        int v = (t >= off) ? buf[t - off] : 0;
        __syncthreads();
        buf[t] += v;
        __syncthreads();
    }
    if (i < n) start[i + 1] = bsum[b] + buf[t];
    if (i == 0) start[0] = 0;
}

__global__ void copy_int_kernel(const int* __restrict__ a, int* b, int n) {
    int i = blockIdx.x * blockDim.x + threadIdx.x;
    if (i < n) b[i] = a[i];
}
__global__ void fill_kernel(const int* __restrict__ row, const int* __restrict__ col,
                            int* cursor, int* __restrict__ esrc, int E) {
    int e = blockIdx.x * blockDim.x + threadIdx.x;
    if (e >= E) return;
    int c = col[e];
    int p = atomicAdd(&cursor[c], 1);
    esrc[p] = row[e];
}

// ---------------- glob init ----------------
__global__ void glob_tile_kernel(const float* __restrict__ gi, float* glob) {
    glob[blockIdx.x * GDIM + threadIdx.x] = gi[threadIdx.x];
}

// ---------------- gn = glob @ Wgn + bgn (layer 0 only) ----------------
template <int DOUT>
__global__ __launch_bounds__(1024) void gn_kernel(const float* __restrict__ glob,
                                                  const float* __restrict__ Wgn,
                                                  const float* __restrict__ bgn,
                                                  float* __restrict__ gn) {
    constexpr int Q = 1024 / DOUT;
    constexpr int KS = GDIM / Q;
    __shared__ float gr[GDIM];
    __shared__ float red[Q][DOUT];
    int g = blockIdx.x, tid = threadIdx.x;
    if (tid < GDIM) gr[tid] = glob[g * GDIM + tid];
    __syncthreads();
    int j = tid % DOUT, q = tid / DOUT;
    float s = 0.f;
    #pragma unroll
    for (int k = 0; k < KS; ++k) {
        int kk = q * KS + k;
        s = fmaf(gr[kk], Wgn[(size_t)kk * DOUT + j], s);
    }
    red[q][j] = s;
    __syncthreads();
    if (q == 0) {
        float r = s + bgn[j];
        #pragma unroll
        for (int t = 1; t < Q; ++t) r += red[t][j];
        gn[(size_t)g * DOUT + j] = r;
    }
}

// ---- fused: parts-reduce + glob update + next-layer gn ----
// block per graph, 512 threads.
template <int DOUT2>
__global__ __launch_bounds__(512) void glob_fused_kernel(
    const float* __restrict__ glob, const float* __restrict__ Wgg,
    const float* __restrict__ bgg, const float* __restrict__ pp,  // [NG][16][256]
    const float* __restrict__ Wng, const float* __restrict__ bng,
    const float* __restrict__ Wgn2, const float* __restrict__ bgn2,
    float* __restrict__ outg, float* __restrict__ gn2) {
    __shared__ float gr[GDIM];
    __shared__ float pr[256];
    __shared__ float red[4 * GDIM];
    __shared__ float gor[GDIM];
    int g = blockIdx.x, tid = threadIdx.x;
    if (tid < GDIM) gr[tid] = glob[g * GDIM + tid];
    if (tid < 256) {
        float m = -INFINITY;
        const float* base = pp + (size_t)g * 16 * 256 + tid;
        #pragma unroll
        for (int c = 0; c < 16; ++c) m = fmaxf(m, base[c * 256]);
        pr[tid] = m;
    }
    __syncthreads();
    int j = tid & 127, q = tid >> 7;
    float s = 0.f;
    #pragma unroll
    for (int k = 0; k < 32; ++k) {
        int kk = q * 32 + k;
        s = fmaf(gr[kk], Wgg[(size_t)kk * GDIM + j], s);
    }
    #pragma unroll
    for (int k = 0; k < 64; ++k) {
        int kk = q * 64 + k;
        s = fmaf(pr[kk], Wng[(size_t)kk * GDIM + j], s);
    }
    red[q * GDIM + j] = s;
    __syncthreads();
    if (q == 0) {
        float o = red[0 * GDIM + j] + red[1 * GDIM + j] + red[2 * GDIM + j] + red[3 * GDIM + j]
                + bgg[j] + bng[j];
        outg[(size_t)g * GDIM + j] = o;
        gor[j] = o;
    }
    __syncthreads();
    // gn2 = gor @ Wgn2 + bgn2
    constexpr int Q2 = 512 / DOUT2;   // 2 (256) or 8 (64)
    constexpr int KS2 = GDIM / Q2;    // 64 or 16
    int j2 = tid % DOUT2, q2 = tid / DOUT2;
    float s2 = 0.f;
    #pragma unroll
    for (int k = 0; k < KS2; ++k) {
        int kk = q2 * KS2 + k;
        s2 = fmaf(gor[kk], Wgn2[(size_t)kk * DOUT2 + j2], s2);
    }
    red[tid] = s2;
    __syncthreads();
    if (q2 == 0) {
        float r = s2 + bgn2[j2];
        #pragma unroll
        for (int t = 1; t < Q2; ++t) r += red[t * DOUT2 + j2];
        gn2[(size_t)g * DOUT2 + j2] = r;
    }
}

// ---------------- x -> bf16 ----------------
__global__ void cvtx_kernel(const float* __restrict__ x, unsigned short* __restrict__ xb,
                            int total4) {
    int i = blockIdx.x * blockDim.x + threadIdx.x;
    if (i >= total4) return;
    float4 v = ((const float4*)x)[i];
    ushort4 o;
    o.x = f2b(v.x); o.y = f2b(v.y); o.z = f2b(v.z); o.w = f2b(v.w);
    ((ushort4*)xb)[i] = o;
}

// ---------------- W [K][DOUT] fp32 -> Wt [DOUT][K] bf16 ----------------
__global__ void wtrans_kernel(const float* __restrict__ W, unsigned short* __restrict__ Wt,
                              int K, int DOUT) {
    __shared__ float t[32][33];
    int k0 = blockIdx.x * 32, c0 = blockIdx.y * 32;
    int tx = threadIdx.x, ty = threadIdx.y;
    #pragma unroll
    for (int i = 0; i < 4; ++i)
        t[ty + i * 8][tx] = W[(size_t)(k0 + ty + i * 8) * DOUT + c0 + tx];
    __syncthreads();
    #pragma unroll
    for (int i = 0; i < 4; ++i)
        Wt[(size_t)(c0 + ty + i * 8) * K + k0 + tx] = f2b(t[tx][ty + i * 8]);
}

// ---------------- MFMA GEMM: Cb(bf16) = relu?(A) @ Wt^T + bias + gn[ga] ----------------
template <int BM, int BN>
__global__ __launch_bounds__(256) void mfma_gemm_kernel(
    const unsigned short* __restrict__ A, const unsigned short* __restrict__ Wt,
    const float* __restrict__ bias, const float* __restrict__ gn,
    const int* __restrict__ ga, unsigned short* __restrict__ Cb,
    int N, int K, int relu)
{
    __shared__ unsigned short Alds[BM * 32];
    __shared__ unsigned short Blds[BN * 32];
    int tid = threadIdx.x;
    int lane = tid & 63, wave = tid >> 6;
    constexpr int WN = BN / 64;
    int wm = wave / WN, wn = wave % WN;
    int row0 = blockIdx.x * BM;
    f32x4 acc[4][4];
    #pragma unroll
    for (int i = 0; i < 4; ++i)
        #pragma unroll
        for (int j = 0; j < 4; ++j) acc[i][j] = (f32x4){0.f, 0.f, 0.f, 0.f};

    for (int k0 = 0; k0 < K; k0 += 32) {
        #pragma unroll
        for (int i = 0; i < BM / 64; ++i) {
            int s = tid + i * 256;
            int mf = s >> 6, kg = (s >> 4) & 3, r = s & 15;
            int grow = row0 + mf * 16 + r;
            int4 v = (int4){0, 0, 0, 0};
            if (grow < N) v = *(const int4*)(A + (size_t)grow * K + k0 + kg * 8);
            if (relu) {
                unsigned short* p = (unsigned short*)&v;
                #pragma unroll
                for (int q = 0; q < 8; ++q) p[q] = (p[q] & 0x8000) ? (unsigned short)0 : p[q];
            }
            *(int4*)(Alds + (size_t)s * 8) = v;
        }
        #pragma unroll
        for (int i = 0; i < BN / 64; ++i) {
            int s = tid + i * 256;
            int nf = s >> 6, kg = (s >> 4) & 3, c = s & 15;
            int col = nf * 16 + c;
            int4 v = *(const int4*)(Wt + (size_t)col * K + k0 + kg * 8);
            *(int4*)(Blds + (size_t)s * 8) = v;
        }
        __syncthreads();
        bf16x8 af[4], bfr[4];
        #pragma unroll
        for (int m = 0; m < 4; ++m)
            af[m] = *(const bf16x8*)(Alds + (size_t)(((wm * 4 + m) * 4 + (lane >> 4)) * 16 + (lane & 15)) * 8);
        #pragma unroll
        for (int nn = 0; nn < 4; ++nn)
            bfr[nn] = *(const bf16x8*)(Blds + (size_t)(((wn * 4 + nn) * 4 + (lane >> 4)) * 16 + (lane & 15)) * 8);
        #pragma unroll
        for (int m = 0; m < 4; ++m)
            #pragma unroll
            for (int nn = 0; nn < 4; ++nn)
                acc[m][nn] = __builtin_amdgcn_mfma_f32_16x16x32_bf16(af[m], bfr[nn], acc[m][nn], 0, 0, 0);
        __syncthreads();
    }

    int cbase = lane & 15;
    float bb[4];
    #pragma unroll
    for (int nn = 0; nn < 4; ++nn) bb[nn] = bias[(wn * 4 + nn) * 16 + cbase];
    #pragma unroll
    for (int m = 0; m < 4; ++m) {
        int rb = row0 + (wm * 4 + m) * 16 + (lane >> 4) * 4;
        #pragma unroll
        for (int reg = 0; reg < 4; ++reg) {
            int r = rb + reg;
            if (r < N) {
                int g = ga[r];
                const float* gnr = gn + (size_t)g * BN;
                #pragma unroll
                for (int nn = 0; nn < 4; ++nn) {
                    int col = (wn * 4 + nn) * 16 + cbase;
                    Cb[(size_t)r * BN + col] = f2b(acc[m][nn][reg] + bb[nn] + gnr[col]);
                }
            }
        }
    }
}

// ---------------- gather 256-wide, 4x-unrolled edge loop ----------------
__global__ void gather256_kernel(const unsigned short* __restrict__ tmp,
                                 unsigned short* __restrict__ outp,
                                 const int* __restrict__ start, const int* __restrict__ esrc,
                                 const float* __restrict__ dinv, int n) {
    int gt = blockIdx.x * blockDim.x + threadIdx.x;
    int node = gt >> 6;
    if (node >= n) return;
    int lane = gt & 63;
    float dc = dinv[node];
    ushort4 v = ((const ushort4*)(tmp + (size_t)node * 256))[lane];
    float s0 = dc * dc;
    float a0 = s0 * b2f(v.x), a1 = s0 * b2f(v.y), a2 = s0 * b2f(v.z), a3 = s0 * b2f(v.w);
    int a = start[node], b = start[node + 1];
    int j = a;
    for (; j + 4 <= b; j += 4) {
        int r0 = esrc[j], r1 = esrc[j + 1], r2 = esrc[j + 2], r3 = esrc[j + 3];
        float n0 = dc * dinv[r0], n1 = dc * dinv[r1], n2 = dc * dinv[r2], n3 = dc * dinv[r3];
        ushort4 u0 = ((const ushort4*)(tmp + (size_t)r0 * 256))[lane];
        ushort4 u1 = ((const ushort4*)(tmp + (size_t)r1 * 256))[lane];
        ushort4 u2 = ((const ushort4*)(tmp + (size_t)r2 * 256))[lane];
        ushort4 u3 = ((const ushort4*)(tmp + (size_t)r3 * 256))[lane];
        a0 = fmaf(n0, b2f(u0.x), a0); a1 = fmaf(n0, b2f(u0.y), a1);
        a2 = fmaf(n0, b2f(u0.z), a2); a3 = fmaf(n0, b2f(u0.w), a3);
        a0 = fmaf(n1, b2f(u1.x), a0); a1 = fmaf(n1, b2f(u1.y), a1);
        a2 = fmaf(n1, b2f(u1.z), a2); a3 = fmaf(n1, b2f(u1.w), a3);
        a0 = fmaf(n2, b2f(u2.x), a0); a1 = fmaf(n2, b2f(u2.y), a1);
        a2 = fmaf(n2, b2f(u2.z), a2); a3 = fmaf(n2, b2f(u2.w), a3);
        a0 = fmaf(n3, b2f(u3.x), a0); a1 = fmaf(n3, b2f(u3.y), a1);
        a2 = fmaf(n3, b2f(u3.z), a2); a3 = fmaf(n3, b2f(u3.w), a3);
    }
    for (; j < b; ++j) {
        int r = esrc[j];
        float nrm = dc * dinv[r];
        ushort4 u = ((const ushort4*)(tmp + (size_t)r * 256))[lane];
        a0 = fmaf(nrm, b2f(u.x), a0);
        a1 = fmaf(nrm, b2f(u.y), a1);
        a2 = fmaf(nrm, b2f(u.z), a2);
        a3 = fmaf(nrm, b2f(u.w), a3);
    }
    ushort4 o;
    o.x = f2b(a0); o.y = f2b(a1); o.z = f2b(a2); o.w = f2b(a3);
    ((ushort4*)(outp + (size_t)node * 256))[lane] = o;
}

// ---------------- gather 64-wide + sigmoid, 4x-unrolled ----------------
__global__ void gather64_kernel(const unsigned short* __restrict__ tmp,
                                float* __restrict__ outp,
                                const int* __restrict__ start, const int* __restrict__ esrc,
                                const float* __restrict__ dinv, int n) {
    int gt = blockIdx.x * blockDim.x + threadIdx.x;
    int node = gt >> 4;
    if (node >= n) return;
    int lane = gt & 15;
    float dc = dinv[node];
    ushort4 v = ((const ushort4*)(tmp + (size_t)node * 64))[lane];
    float s0 = dc * dc;
    float a0 = s0 * b2f(v.x), a1 = s0 * b2f(v.y), a2 = s0 * b2f(v.z), a3 = s0 * b2f(v.w);
    int a = start[node], b = start[node + 1];
    int j = a;
    for (; j + 4 <= b; j += 4) {
        int r0 = esrc[j], r1 = esrc[j + 1], r2 = esrc[j + 2], r3 = esrc[j + 3];
        float n0 = dc * dinv[r0], n1 = dc * dinv[r1], n2 = dc * dinv[r2], n3 = dc * dinv[r3];
        ushort4 u0 = ((const ushort4*)(tmp + (size_t)r0 * 64))[lane];
        ushort4 u1 = ((const ushort4*)(tmp + (size_t)r1 * 64))[lane];
        ushort4 u2 = ((const ushort4*)(tmp + (size_t)r2 * 64))[lane];
        ushort4 u3 = ((const ushort4*)(tmp + (size_t)r3 * 64))[lane];
        a0 = fmaf(n0, b2f(u0.x), a0); a1 = fmaf(n0, b2f(u0.y), a1);
        a2 = fmaf(n0, b2f(u0.z), a2); a3 = fmaf(n0, b2f(u0.w), a3);
        a0 = fmaf(n1, b2f(u1.x), a0); a1 = fmaf(n1, b2f(u1.y), a1);
        a2 = fmaf(n1, b2f(u1.z), a2); a3 = fmaf(n1, b2f(u1.w), a3);
        a0 = fmaf(n2, b2f(u2.x), a0); a1 = fmaf(n2, b2f(u2.y), a1);
        a2 = fmaf(n2, b2f(u2.z), a2); a3 = fmaf(n2, b2f(u2.w), a3);
        a0 = fmaf(n3, b2f(u3.x), a0); a1 = fmaf(n3, b2f(u3.y), a1);
        a2 = fmaf(n3, b2f(u3.z), a2); a3 = fmaf(n3, b2f(u3.w), a3);
    }
    for (; j < b; ++j) {
        int r = esrc[j];
        float nrm = dc * dinv[r];
        ushort4 u = ((const ushort4*)(tmp + (size_t)r * 64))[lane];
        a0 = fmaf(nrm, b2f(u.x), a0);
        a1 = fmaf(nrm, b2f(u.y), a1);
        a2 = fmaf(nrm, b2f(u.z), a2);
        a3 = fmaf(nrm, b2f(u.w), a3);
    }
    float4 o;
    o.x = 1.0f / (1.0f + expf(-a0));
    o.y = 1.0f / (1.0f + expf(-a1));
    o.z = 1.0f / (1.0f + expf(-a2));
    o.w = 1.0f / (1.0f + expf(-a3));
    ((float4*)(outp + (size_t)node * 64))[lane] = o;
}

// ---------------- per-graph max partials on bf16 h ----------------
__global__ void parts_partial_kernel(const unsigned short* __restrict__ h,
                                     const int* __restrict__ ga,
                                     float* __restrict__ pp, int n, int dout) {
    int g = blockIdx.x, ch = blockIdx.y, nch = gridDim.y;
    int lo = 0, hi = n;
    while (lo < hi) { int m = (lo + hi) >> 1; if (ga[m] < g) lo = m + 1; else hi = m; }
    int s = lo;
    lo = s; hi = n;
    while (lo < hi) { int m = (lo + hi) >> 1; if (ga[m] <= g) lo = m + 1; else hi = m; }
    int epos = lo;
    int cnt = epos - s;
    int per = (cnt + nch - 1) / nch;
    int a = s + ch * per;
    int b = min(epos, a + per);
    for (int j = threadIdx.x; j < dout; j += blockDim.x) {
        float m = -INFINITY;
        for (int i = a; i < b; ++i) m = fmaxf(m, b2f(h[(size_t)i * dout + j]));
        pp[((size_t)g * nch + ch) * dout + j] = m;
    }
}

extern "C" void kernel_launch(void* const* d_in, const int* in_sizes, int n_in,
                              void* d_out, int out_size, void* d_ws, size_t ws_size,
                              hipStream_t stream) {
    const float* x         = (const float*)d_in[0];
    const int*   ei        = (const int*)d_in[1];
    const int*   ga        = (const int*)d_in[2];
    const float* glob_init = (const float*)d_in[3];

    const int n = in_sizes[0] / 128;   // 50000
    const int E = in_sizes[1] / 2;     // 400000
    const int* row = ei;               // sources
    const int* col = ei + E;           // targets

    float* ws = (float*)d_ws;
    size_t off = 0;
    auto alloc = [&](size_t cnt) { float* p = ws + off; off += cnt; return p; };
    unsigned short* tb    = (unsigned short*)alloc((size_t)n * 128);
    unsigned short* hb    = (unsigned short*)alloc((size_t)n * 128);
    unsigned short* xb    = (unsigned short*)alloc((size_t)n * 64);
    unsigned short* Wt    = (unsigned short*)alloc((size_t)32768);
    float* dinv  = alloc((size_t)n);
    float* gnbuf = alloc((size_t)NG * 256);
    float* pp    = alloc((size_t)NG * 16 * 256);
    float* globA = alloc((size_t)NG * GDIM);
    float* globB = alloc((size_t)NG * GDIM);
    int* cnt    = (int*)alloc((size_t)n);
    int* startA = (int*)alloc((size_t)n + 1);
    int* cursor = (int*)alloc((size_t)n);
    int* esrc   = (int*)alloc((size_t)E);
    int* bsum   = (int*)alloc((size_t)SCAN_BS);
    (void)ws_size; (void)n_in; (void)out_size;

    const int nb = (n + SCAN_BS - 1) / SCAN_BS;

    // ---- CSR build ----
    zero_int_kernel<<<(n + 255) / 256, 256, 0, stream>>>(cnt, n);
    count_kernel<<<(E + 255) / 256, 256, 0, stream>>>(col, cnt, E);
    dinv_kernel<<<(n + 255) / 256, 256, 0, stream>>>(cnt, dinv, n);
    scan_partial_kernel<<<nb, SCAN_BS, 0, stream>>>(cnt, bsum, n);
    scan_bsum_kernel<<<1, SCAN_BS, 0, stream>>>(bsum, nb);
    scan_final_kernel<<<nb, SCAN_BS, 0, stream>>>(cnt, bsum, startA, n);
    copy_int_kernel<<<(n + 255) / 256, 256, 0, stream>>>(startA, cursor, n);
    fill_kernel<<<(E + 255) / 256, 256, 0, stream>>>(row, col, cursor, esrc, E);

    glob_tile_kernel<<<NG, GDIM, 0, stream>>>(glob_init, globA);
    cvtx_kernel<<<((size_t)n * 32 + 255) / 256, 256, 0, stream>>>(x, xb, n * 32);

    float* gcur = globA;
    float* gnext = globB;
    int K = 128;
    for (int li = 0; li < 3; ++li) {
        const float* Wnn = (const float*)d_in[4 + li * 8 + 0];
        const float* bnn = (const float*)d_in[4 + li * 8 + 1];
        const float* Wgn = (const float*)d_in[4 + li * 8 + 2];
        const float* bgn = (const float*)d_in[4 + li * 8 + 3];
        const float* Wgg = (const float*)d_in[4 + li * 8 + 4];
        const float* bgg = (const float*)d_in[4 + li * 8 + 5];
        const float* Wng = (const float*)d_in[4 + li * 8 + 6];
        const float* bng = (const float*)d_in[4 + li * 8 + 7];
        const int dout = (li == 2) ? 64 : 256;

        dim3 wtg(K / 32, dout / 32);
        wtrans_kernel<<<wtg, dim3(32, 8), 0, stream>>>(Wnn, Wt, K, dout);
        if (li == 0)
            gn_kernel<256><<<NG, 1024, 0, stream>>>(gcur, Wgn, bgn, gnbuf);
        // li=1,2: gnbuf was produced by the previous glob_fused_kernel

        if (li == 0) {
            mfma_gemm_kernel<64, 256><<<(n + 63) / 64, 256, 0, stream>>>(
                xb, Wt, bnn, gnbuf, ga, tb, n, 128, 0);
        } else if (li == 1) {
            mfma_gemm_kernel<64, 256><<<(n + 63) / 64, 256, 0, stream>>>(
                hb, Wt, bnn, gnbuf, ga, tb, n, 256, 1);
        } else {
            mfma_gemm_kernel<256, 64><<<(n + 255) / 256, 256, 0, stream>>>(
                hb, Wt, bnn, gnbuf, ga, tb, n, 256, 1);
        }

        if (li < 2) {
            gather256_kernel<<<((size_t)n * 64 + 255) / 256, 256, 0, stream>>>(
                tb, hb, startA, esrc, dinv, n);
            dim3 pgrid(NG, 16);
            parts_partial_kernel<<<pgrid, 256, 0, stream>>>(hb, ga, pp, n, dout);
            const float* Wgn2 = (const float*)d_in[4 + (li + 1) * 8 + 2];
            const float* bgn2 = (const float*)d_in[4 + (li + 1) * 8 + 3];
            if (li == 0)
                glob_fused_kernel<256><<<NG, 512, 0, stream>>>(
                    gcur, Wgg, bgg, pp, Wng, bng, Wgn2, bgn2, gnext, gnbuf);
            else
                glob_fused_kernel<64><<<NG, 512, 0, stream>>>(
                    gcur, Wgg, bgg, pp, Wng, bng, Wgn2, bgn2, gnext, gnbuf);
            float* t = gcur; gcur = gnext; gnext = t;
        } else {
            gather64_kernel<<<((size_t)n * 16 + 255) / 256, 256, 0, stream>>>(
                tb, (float*)d_out, startA, esrc, dinv, n);
        }
        K = dout;
    }
}

// Round 7
// 297.317 us; speedup vs baseline: 1.4628x; 1.0341x over previous
//
#include <hip/hip_runtime.h>
#include <math.h>
#include <float.h>

#define NG 64
#define GDIM 128

typedef short bf16x8 __attribute__((ext_vector_type(8)));
typedef float f32x4 __attribute__((ext_vector_type(4)));

__device__ inline unsigned short f2b(float f) {
    unsigned u = __builtin_bit_cast(unsigned, f);
    unsigned r = u + 0x7FFFu + ((u >> 16) & 1u);
    return (unsigned short)(r >> 16);
}
__device__ inline float b2f(unsigned short b) {
    unsigned u = ((unsigned)b) << 16;
    return __builtin_bit_cast(float, u);
}

// async global->LDS, 16B per lane; LDS dest = wave-uniform base + lane*16
__device__ __forceinline__ void gl_lds16(const unsigned short* g, unsigned short* l) {
    __builtin_amdgcn_global_load_lds(
        (const __attribute__((address_space(1))) unsigned int*)g,
        (__attribute__((address_space(3))) unsigned int*)l,
        16, 0, 0);
}

// ================= fused setup =================
// blocks [0,B0): zero cnt ; [B0,B0+B1): cvtx ; +32: glob tile ; +1: gn0 ; +112: wtrans x3
__global__ __launch_bounds__(256) void setup_kernel(
    int n, int total4,
    const float* __restrict__ x, unsigned short* __restrict__ xb,
    const float* __restrict__ gi, float* __restrict__ glob, int* __restrict__ cnt,
    const float* __restrict__ Wgn0, const float* __restrict__ bgn0, float* __restrict__ gnbuf,
    const float* __restrict__ W0, unsigned short* __restrict__ Wt0,
    const float* __restrict__ W1, unsigned short* __restrict__ Wt1,
    const float* __restrict__ W2, unsigned short* __restrict__ Wt2,
    int B0, int B1)
{
    int b = blockIdx.x, tid = threadIdx.x;
    if (b < B0) { int i = b * 256 + tid; if (i < n) cnt[i] = 0; return; }
    b -= B0;
    if (b < B1) {
        int i = b * 256 + tid;
        if (i < total4) {
            float4 v = ((const float4*)x)[i];
            ushort4 o;
            o.x = f2b(v.x); o.y = f2b(v.y); o.z = f2b(v.z); o.w = f2b(v.w);
            ((ushort4*)xb)[i] = o;
        }
        return;
    }
    b -= B1;
    if (b < 32) { int i = b * 256 + tid; glob[i] = gi[i & 127]; return; }
    b -= 32;
    if (b < 1) {
        // L0 gn: identical for all graphs (glob == tile(glob_init))
        float s = bgn0[tid];
        for (int k = 0; k < GDIM; ++k) s = fmaf(gi[k], Wgn0[(size_t)k * 256 + tid], s);
        for (int g = 0; g < NG; ++g) gnbuf[(size_t)g * 256 + tid] = s;
        return;
    }
    b -= 1;
    const float* W; unsigned short* Wt; int K, D, kx, cy;
    if (b < 32)      { W = W0; Wt = Wt0; K = 128; D = 256; kx = b & 3;  cy = b >> 2; }
    else if (b < 96) { int l = b - 32; W = W1; Wt = Wt1; K = 256; D = 256; kx = l & 7; cy = l >> 3; }
    else             { int l = b - 96; W = W2; Wt = Wt2; K = 256; D = 64;  kx = l & 7; cy = l >> 3; }
    __shared__ float t[32][33];
    int tx = tid & 31, ty = tid >> 5;
    int k0 = kx * 32, c0 = cy * 32;
    #pragma unroll
    for (int i = 0; i < 4; ++i)
        t[ty + i * 8][tx] = W[(size_t)(k0 + ty + i * 8) * D + c0 + tx];
    __syncthreads();
    #pragma unroll
    for (int i = 0; i < 4; ++i)
        Wt[(size_t)(c0 + ty + i * 8) * K + k0 + tx] = f2b(t[tx][ty + i * 8]);
}

// ================= CSR build =================
__global__ void count_kernel(const int* __restrict__ col, int* cnt, int E) {
    int i = blockIdx.x * blockDim.x + threadIdx.x;
    if (i < E) atomicAdd(&cnt[col[i]], 1);
}

#define SCAN_BS 256
__global__ void scan_partial_kernel(const int* __restrict__ cnt, int* __restrict__ bsum,
                                    float* __restrict__ dinv, int n) {
    __shared__ int red[SCAN_BS];
    int i = blockIdx.x * SCAN_BS + threadIdx.x;
    int v = (i < n) ? cnt[i] : 0;
    if (i < n) dinv[i] = rsqrtf((float)v + 1.0f);
    red[threadIdx.x] = v;
    __syncthreads();
    #pragma unroll
    for (int off = SCAN_BS / 2; off > 0; off >>= 1) {
        if (threadIdx.x < off) red[threadIdx.x] += red[threadIdx.x + off];
        __syncthreads();
    }
    if (threadIdx.x == 0) bsum[blockIdx.x] = red[0];
}
__global__ __launch_bounds__(SCAN_BS) void scan_bsum_kernel(int* bsum, int nb) {
    __shared__ int buf[SCAN_BS];
    int t = threadIdx.x;
    buf[t] = (t < nb) ? bsum[t] : 0;
    __syncthreads();
    #pragma unroll
    for (int off = 1; off < SCAN_BS; off <<= 1) {
        int v = (t >= off) ? buf[t - off] : 0;
        __syncthreads();
        buf[t] += v;
        __syncthreads();
    }
    int ex = (t == 0) ? 0 : buf[t - 1];
    if (t < nb) bsum[t] = ex;
}
__global__ void scan_final_kernel(const int* __restrict__ cnt, const int* __restrict__ bsum,
                                  int* __restrict__ start, int* __restrict__ cursor, int n) {
    __shared__ int buf[SCAN_BS];
    int b = blockIdx.x, t = threadIdx.x;
    int i = b * SCAN_BS + t;
    int v = (i < n) ? cnt[i] : 0;
    buf[t] = v;
    __syncthreads();
    #pragma unroll
    for (int off = 1; off < SCAN_BS; off <<= 1) {
        int u = (t >= off) ? buf[t - off] : 0;
        __syncthreads();
        buf[t] += u;
        __syncthreads();
    }
    if (i < n) {
        int inc = bsum[b] + buf[t];
        start[i + 1] = inc;
        cursor[i] = inc - v;
    }
    if (i == 0) start[0] = 0;
}
__global__ void fill_kernel(const int* __restrict__ row, const int* __restrict__ col,
                            int* cursor, int* __restrict__ esrc, int E) {
    int e = blockIdx.x * blockDim.x + threadIdx.x;
    if (e >= E) return;
    int c = col[e];
    int p = atomicAdd(&cursor[c], 1);
    esrc[p] = row[e];
}

// ---- fused: parts-reduce + glob update + next-layer gn ----
template <int DOUT2>
__global__ __launch_bounds__(512) void glob_fused_kernel(
    const float* __restrict__ glob, const float* __restrict__ Wgg,
    const float* __restrict__ bgg, const float* __restrict__ pp,
    const float* __restrict__ Wng, const float* __restrict__ bng,
    const float* __restrict__ Wgn2, const float* __restrict__ bgn2,
    float* __restrict__ outg, float* __restrict__ gn2) {
    __shared__ float gr[GDIM];
    __shared__ float pr[256];
    __shared__ float red[4 * GDIM];
    __shared__ float gor[GDIM];
    int g = blockIdx.x, tid = threadIdx.x;
    if (tid < GDIM) gr[tid] = glob[g * GDIM + tid];
    if (tid < 256) {
        float m = -INFINITY;
        const float* base = pp + (size_t)g * 16 * 256 + tid;
        #pragma unroll
        for (int c = 0; c < 16; ++c) m = fmaxf(m, base[c * 256]);
        pr[tid] = m;
    }
    __syncthreads();
    int j = tid & 127, q = tid >> 7;
    float s = 0.f;
    #pragma unroll
    for (int k = 0; k < 32; ++k) {
        int kk = q * 32 + k;
        s = fmaf(gr[kk], Wgg[(size_t)kk * GDIM + j], s);
    }
    #pragma unroll
    for (int k = 0; k < 64; ++k) {
        int kk = q * 64 + k;
        s = fmaf(pr[kk], Wng[(size_t)kk * GDIM + j], s);
    }
    red[q * GDIM + j] = s;
    __syncthreads();
    if (q == 0) {
        float o = red[0 * GDIM + j] + red[1 * GDIM + j] + red[2 * GDIM + j] + red[3 * GDIM + j]
                + bgg[j] + bng[j];
        outg[(size_t)g * GDIM + j] = o;
        gor[j] = o;
    }
    __syncthreads();
    constexpr int Q2 = 512 / DOUT2;
    constexpr int KS2 = GDIM / Q2;
    int j2 = tid % DOUT2, q2 = tid / DOUT2;
    float s2 = 0.f;
    #pragma unroll
    for (int k = 0; k < KS2; ++k) {
        int kk = q2 * KS2 + k;
        s2 = fmaf(gor[kk], Wgn2[(size_t)kk * DOUT2 + j2], s2);
    }
    red[tid] = s2;
    __syncthreads();
    if (q2 == 0) {
        float r = s2 + bgn2[j2];
        #pragma unroll
        for (int t = 1; t < Q2; ++t) r += red[t * DOUT2 + j2];
        gn2[(size_t)g * DOUT2 + j2] = r;
    }
}

// ================= MFMA GEMM with global_load_lds staging =================
template <int BM, int BN>
__global__ __launch_bounds__(256) void mfma_gemm_kernel(
    const unsigned short* __restrict__ A, const unsigned short* __restrict__ Wt,
    const float* __restrict__ bias, const float* __restrict__ gn,
    const int* __restrict__ ga, unsigned short* __restrict__ Cb,
    int N, int K)
{
    __shared__ unsigned short Alds[BM * 32];
    __shared__ unsigned short Blds[BN * 32];
    int tid = threadIdx.x;
    int lane = tid & 63, wave = tid >> 6;
    constexpr int WN = BN / 64;
    int wm = wave / WN, wn = wave % WN;
    int row0 = blockIdx.x * BM;
    f32x4 acc[4][4];
    #pragma unroll
    for (int i = 0; i < 4; ++i)
        #pragma unroll
        for (int j = 0; j < 4; ++j) acc[i][j] = (f32x4){0.f, 0.f, 0.f, 0.f};

    for (int k0 = 0; k0 < K; k0 += 32) {
        // A: slots s = tid + i*256 ; dest byte = s*16 ; wave base uniform
        #pragma unroll
        for (int i = 0; i < BM / 64; ++i) {
            int s = tid + i * 256;
            int mf = s >> 6, kg = (s >> 4) & 3, r = s & 15;
            const unsigned short* src = A + (size_t)(row0 + mf * 16 + r) * K + k0 + kg * 8;
            gl_lds16(src, Alds + (size_t)(i * 256 + wave * 64) * 8);
        }
        #pragma unroll
        for (int i = 0; i < BN / 64; ++i) {
            int s = tid + i * 256;
            int nf = s >> 6, kg = (s >> 4) & 3, c = s & 15;
            const unsigned short* src = Wt + (size_t)(nf * 16 + c) * K + k0 + kg * 8;
            gl_lds16(src, Blds + (size_t)(i * 256 + wave * 64) * 8);
        }
        __syncthreads();
        bf16x8 af[4], bfr[4];
        #pragma unroll
        for (int m = 0; m < 4; ++m)
            af[m] = *(const bf16x8*)(Alds + (size_t)(((wm * 4 + m) * 4 + (lane >> 4)) * 16 + (lane & 15)) * 8);
        #pragma unroll
        for (int nn = 0; nn < 4; ++nn)
            bfr[nn] = *(const bf16x8*)(Blds + (size_t)(((wn * 4 + nn) * 4 + (lane >> 4)) * 16 + (lane & 15)) * 8);
        #pragma unroll
        for (int m = 0; m < 4; ++m)
            #pragma unroll
            for (int nn = 0; nn < 4; ++nn)
                acc[m][nn] = __builtin_amdgcn_mfma_f32_16x16x32_bf16(af[m], bfr[nn], acc[m][nn], 0, 0, 0);
        __syncthreads();
    }

    int cbase = lane & 15;
    float bb[4];
    #pragma unroll
    for (int nn = 0; nn < 4; ++nn) bb[nn] = bias[(wn * 4 + nn) * 16 + cbase];
    #pragma unroll
    for (int m = 0; m < 4; ++m) {
        int rb = row0 + (wm * 4 + m) * 16 + (lane >> 4) * 4;
        #pragma unroll
        for (int reg = 0; reg < 4; ++reg) {
            int r = rb + reg;
            if (r < N) {
                int g = ga[r];
                const float* gnr = gn + (size_t)g * BN;
                #pragma unroll
                for (int nn = 0; nn < 4; ++nn) {
                    int col = (wn * 4 + nn) * 16 + cbase;
                    Cb[(size_t)r * BN + col] = f2b(acc[m][nn][reg] + bb[nn] + gnr[col]);
                }
            }
        }
    }
}

// ================= gather 256-wide, 8x/4x-unrolled, dual output =================
#define EDGE4(RA, RB, RC, RD)                                                       \
    {                                                                               \
        float n0 = dc * dinv[RA], n1 = dc * dinv[RB], n2 = dc * dinv[RC], n3 = dc * dinv[RD]; \
        ushort4 u0 = ((const ushort4*)(tmp + (size_t)(RA) * 256))[lane];            \
        ushort4 u1 = ((const ushort4*)(tmp + (size_t)(RB) * 256))[lane];            \
        ushort4 u2 = ((const ushort4*)(tmp + (size_t)(RC) * 256))[lane];            \
        ushort4 u3 = ((const ushort4*)(tmp + (size_t)(RD) * 256))[lane];            \
        a0 = fmaf(n0, b2f(u0.x), a0); a1 = fmaf(n0, b2f(u0.y), a1);                 \
        a2 = fmaf(n0, b2f(u0.z), a2); a3 = fmaf(n0, b2f(u0.w), a3);                 \
        a0 = fmaf(n1, b2f(u1.x), a0); a1 = fmaf(n1, b2f(u1.y), a1);                 \
        a2 = fmaf(n1, b2f(u1.z), a2); a3 = fmaf(n1, b2f(u1.w), a3);                 \
        a0 = fmaf(n2, b2f(u2.x), a0); a1 = fmaf(n2, b2f(u2.y), a1);                 \
        a2 = fmaf(n2, b2f(u2.z), a2); a3 = fmaf(n2, b2f(u2.w), a3);                 \
        a0 = fmaf(n3, b2f(u3.x), a0); a1 = fmaf(n3, b2f(u3.y), a1);                 \
        a2 = fmaf(n3, b2f(u3.z), a2); a3 = fmaf(n3, b2f(u3.w), a3);                 \
    }

__global__ void gather256_kernel(const unsigned short* __restrict__ tmp,
                                 unsigned short* __restrict__ outR,   // relu'd (GEMM input)
                                 unsigned short* __restrict__ outP,   // pre-relu (parts max)
                                 const int* __restrict__ start, const int* __restrict__ esrc,
                                 const float* __restrict__ dinv, int n) {
    int gt = blockIdx.x * blockDim.x + threadIdx.x;
    int node = gt >> 6;
    if (node >= n) return;
    int lane = gt & 63;
    float dc = dinv[node];
    ushort4 v = ((const ushort4*)(tmp + (size_t)node * 256))[lane];
    float s0 = dc * dc;
    float a0 = s0 * b2f(v.x), a1 = s0 * b2f(v.y), a2 = s0 * b2f(v.z), a3 = s0 * b2f(v.w);
    int a = start[node], b = start[node + 1];
    int j = a;
    for (; j + 8 <= b; j += 8) {
        int r0 = esrc[j], r1 = esrc[j + 1], r2 = esrc[j + 2], r3 = esrc[j + 3];
        int r4 = esrc[j + 4], r5 = esrc[j + 5], r6 = esrc[j + 6], r7 = esrc[j + 7];
        EDGE4(r0, r1, r2, r3)
        EDGE4(r4, r5, r6, r7)
    }
    if (j + 4 <= b) {
        int r0 = esrc[j], r1 = esrc[j + 1], r2 = esrc[j + 2], r3 = esrc[j + 3];
        EDGE4(r0, r1, r2, r3)
        j += 4;
    }
    for (; j < b; ++j) {
        int r = esrc[j];
        float nrm = dc * dinv[r];
        ushort4 u = ((const ushort4*)(tmp + (size_t)r * 256))[lane];
        a0 = fmaf(nrm, b2f(u.x), a0);
        a1 = fmaf(nrm, b2f(u.y), a1);
        a2 = fmaf(nrm, b2f(u.z), a2);
        a3 = fmaf(nrm, b2f(u.w), a3);
    }
    ushort4 op;
    op.x = f2b(a0); op.y = f2b(a1); op.z = f2b(a2); op.w = f2b(a3);
    ((ushort4*)(outP + (size_t)node * 256))[lane] = op;
    ushort4 orl;
    orl.x = f2b(fmaxf(a0, 0.f)); orl.y = f2b(fmaxf(a1, 0.f));
    orl.z = f2b(fmaxf(a2, 0.f)); orl.w = f2b(fmaxf(a3, 0.f));
    ((ushort4*)(outR + (size_t)node * 256))[lane] = orl;
}

#define EDGE4_64(RA, RB, RC, RD)                                                    \
    {                                                                               \
        float n0 = dc * dinv[RA], n1 = dc * dinv[RB], n2 = dc * dinv[RC], n3 = dc * dinv[RD]; \
        ushort4 u0 = ((const ushort4*)(tmp + (size_t)(RA) * 64))[lane];             \
        ushort4 u1 = ((const ushort4*)(tmp + (size_t)(RB) * 64))[lane];             \
        ushort4 u2 = ((const ushort4*)(tmp + (size_t)(RC) * 64))[lane];             \
        ushort4 u3 = ((const ushort4*)(tmp + (size_t)(RD) * 64))[lane];             \
        a0 = fmaf(n0, b2f(u0.x), a0); a1 = fmaf(n0, b2f(u0.y), a1);                 \
        a2 = fmaf(n0, b2f(u0.z), a2); a3 = fmaf(n0, b2f(u0.w), a3);                 \
        a0 = fmaf(n1, b2f(u1.x), a0); a1 = fmaf(n1, b2f(u1.y), a1);                 \
        a2 = fmaf(n1, b2f(u1.z), a2); a3 = fmaf(n1, b2f(u1.w), a3);                 \
        a0 = fmaf(n2, b2f(u2.x), a0); a1 = fmaf(n2, b2f(u2.y), a1);                 \
        a2 = fmaf(n2, b2f(u2.z), a2); a3 = fmaf(n2, b2f(u2.w), a3);                 \
        a0 = fmaf(n3, b2f(u3.x), a0); a1 = fmaf(n3, b2f(u3.y), a1);                 \
        a2 = fmaf(n3, b2f(u3.z), a2); a3 = fmaf(n3, b2f(u3.w), a3);                 \
    }

__global__ void gather64_kernel(const unsigned short* __restrict__ tmp,
                                float* __restrict__ outp,
                                const int* __restrict__ start, const int* __restrict__ esrc,
                                const float* __restrict__ dinv, int n) {
    int gt = blockIdx.x * blockDim.x + threadIdx.x;
    int node = gt >> 4;
    if (node >= n) return;
    int lane = gt & 15;
    float dc = dinv[node];
    ushort4 v = ((const ushort4*)(tmp + (size_t)node * 64))[lane];
    float s0 = dc * dc;
    float a0 = s0 * b2f(v.x), a1 = s0 * b2f(v.y), a2 = s0 * b2f(v.z), a3 = s0 * b2f(v.w);
    int a = start[node], b = start[node + 1];
    int j = a;
    for (; j + 8 <= b; j += 8) {
        int r0 = esrc[j], r1 = esrc[j + 1], r2 = esrc[j + 2], r3 = esrc[j + 3];
        int r4 = esrc[j + 4], r5 = esrc[j + 5], r6 = esrc[j + 6], r7 = esrc[j + 7];
        EDGE4_64(r0, r1, r2, r3)
        EDGE4_64(r4, r5, r6, r7)
    }
    if (j + 4 <= b) {
        int r0 = esrc[j], r1 = esrc[j + 1], r2 = esrc[j + 2], r3 = esrc[j + 3];
        EDGE4_64(r0, r1, r2, r3)
        j += 4;
    }
    for (; j < b; ++j) {
        int r = esrc[j];
        float nrm = dc * dinv[r];
        ushort4 u = ((const ushort4*)(tmp + (size_t)r * 64))[lane];
        a0 = fmaf(nrm, b2f(u.x), a0);
        a1 = fmaf(nrm, b2f(u.y), a1);
        a2 = fmaf(nrm, b2f(u.z), a2);
        a3 = fmaf(nrm, b2f(u.w), a3);
    }
    float4 o;
    o.x = 1.0f / (1.0f + expf(-a0));
    o.y = 1.0f / (1.0f + expf(-a1));
    o.z = 1.0f / (1.0f + expf(-a2));
    o.w = 1.0f / (1.0f + expf(-a3));
    ((float4*)(outp + (size_t)node * 64))[lane] = o;
}

// ---------------- per-graph max partials on bf16 hP ----------------
__global__ void parts_partial_kernel(const unsigned short* __restrict__ h,
                                     const int* __restrict__ ga,
                                     float* __restrict__ pp, int n, int dout) {
    int g = blockIdx.x, ch = blockIdx.y, nch = gridDim.y;
    int lo = 0, hi = n;
    while (lo < hi) { int m = (lo + hi) >> 1; if (ga[m] < g) lo = m + 1; else hi = m; }
    int s = lo;
    lo = s; hi = n;
    while (lo < hi) { int m = (lo + hi) >> 1; if (ga[m] <= g) lo = m + 1; else hi = m; }
    int epos = lo;
    int cnt = epos - s;
    int per = (cnt + nch - 1) / nch;
    int a = s + ch * per;
    int b = min(epos, a + per);
    for (int j = threadIdx.x; j < dout; j += blockDim.x) {
        float m = -INFINITY;
        for (int i = a; i < b; ++i) m = fmaxf(m, b2f(h[(size_t)i * dout + j]));
        pp[((size_t)g * nch + ch) * dout + j] = m;
    }
}

extern "C" void kernel_launch(void* const* d_in, const int* in_sizes, int n_in,
                              void* d_out, int out_size, void* d_ws, size_t ws_size,
                              hipStream_t stream) {
    const float* x         = (const float*)d_in[0];
    const int*   ei        = (const int*)d_in[1];
    const int*   ga        = (const int*)d_in[2];
    const float* glob_init = (const float*)d_in[3];

    const int n = in_sizes[0] / 128;   // 50000
    const int E = in_sizes[1] / 2;     // 400000
    const int* row = ei;               // sources
    const int* col = ei + E;           // targets

    float* ws = (float*)d_ws;
    size_t off = 0;
    auto alloc = [&](size_t cnt_) { float* p = ws + off; off += cnt_; return p; };
    unsigned short* tb  = (unsigned short*)alloc((size_t)n * 128);  // bf16 [N][256]
    unsigned short* hbR = (unsigned short*)alloc((size_t)n * 128);  // relu'd
    unsigned short* hbP = (unsigned short*)alloc((size_t)n * 128);  // pre-relu
    unsigned short* xb  = (unsigned short*)alloc((size_t)n * 64);   // bf16 [N][128]
    unsigned short* Wt0 = (unsigned short*)alloc(16384);            // 128x256
    unsigned short* Wt1 = (unsigned short*)alloc(32768);            // 256x256
    unsigned short* Wt2 = (unsigned short*)alloc(8192);             // 256x64
    float* dinv  = alloc((size_t)n);
    float* gnbuf = alloc((size_t)NG * 256);
    float* pp    = alloc((size_t)NG * 16 * 256);
    float* globA = alloc((size_t)NG * GDIM);
    float* globB = alloc((size_t)NG * GDIM);
    int* cnt    = (int*)alloc((size_t)n);
    int* startA = (int*)alloc((size_t)n + 1);
    int* cursor = (int*)alloc((size_t)n);
    int* esrc   = (int*)alloc((size_t)E);
    int* bsum   = (int*)alloc((size_t)SCAN_BS);
    (void)ws_size; (void)n_in; (void)out_size;

    const int nb = (n + SCAN_BS - 1) / SCAN_BS;
    const int total4 = n * 32;                      // N*128 bf16 / 4
    const int B0 = (n + 255) / 256;
    const int B1 = (total4 + 255) / 256;
    const int NBLK = B0 + B1 + 32 + 1 + 112;

    const float* W0 = (const float*)d_in[4 + 0];
    const float* W1 = (const float*)d_in[4 + 8];
    const float* W2 = (const float*)d_in[4 + 16];
    const float* Wgn0 = (const float*)d_in[4 + 2];
    const float* bgn0 = (const float*)d_in[4 + 3];

    setup_kernel<<<NBLK, 256, 0, stream>>>(n, total4, x, xb, glob_init, globA, cnt,
                                           Wgn0, bgn0, gnbuf,
                                           W0, Wt0, W1, Wt1, W2, Wt2, B0, B1);
    count_kernel<<<(E + 255) / 256, 256, 0, stream>>>(col, cnt, E);
    scan_partial_kernel<<<nb, SCAN_BS, 0, stream>>>(cnt, bsum, dinv, n);
    scan_bsum_kernel<<<1, SCAN_BS, 0, stream>>>(bsum, nb);
    scan_final_kernel<<<nb, SCAN_BS, 0, stream>>>(cnt, bsum, startA, cursor, n);
    fill_kernel<<<(E + 255) / 256, 256, 0, stream>>>(row, col, cursor, esrc, E);

    float* gcur = globA;
    float* gnext = globB;
    for (int li = 0; li < 3; ++li) {
        const float* bnn = (const float*)d_in[4 + li * 8 + 1];
        const float* Wgg = (const float*)d_in[4 + li * 8 + 4];
        const float* bgg = (const float*)d_in[4 + li * 8 + 5];
        const float* Wng = (const float*)d_in[4 + li * 8 + 6];
        const float* bng = (const float*)d_in[4 + li * 8 + 7];

        if (li == 0) {
            mfma_gemm_kernel<64, 256><<<(n + 63) / 64, 256, 0, stream>>>(
                xb, Wt0, bnn, gnbuf, ga, tb, n, 128);
        } else if (li == 1) {
            mfma_gemm_kernel<64, 256><<<(n + 63) / 64, 256, 0, stream>>>(
                hbR, Wt1, bnn, gnbuf, ga, tb, n, 256);
        } else {
            mfma_gemm_kernel<256, 64><<<(n + 255) / 256, 256, 0, stream>>>(
                hbR, Wt2, bnn, gnbuf, ga, tb, n, 256);
        }

        if (li < 2) {
            gather256_kernel<<<((size_t)n * 64 + 255) / 256, 256, 0, stream>>>(
                tb, hbR, hbP, startA, esrc, dinv, n);
            dim3 pgrid(NG, 16);
            parts_partial_kernel<<<pgrid, 256, 0, stream>>>(hbP, ga, pp, n, 256);
            const float* Wgn2 = (const float*)d_in[4 + (li + 1) * 8 + 2];
            const float* bgn2 = (const float*)d_in[4 + (li + 1) * 8 + 3];
            if (li == 0)
                glob_fused_kernel<256><<<NG, 512, 0, stream>>>(
                    gcur, Wgg, bgg, pp, Wng, bng, Wgn2, bgn2, gnext, gnbuf);
            else
                glob_fused_kernel<64><<<NG, 512, 0, stream>>>(
                    gcur, Wgg, bgg, pp, Wng, bng, Wgn2, bgn2, gnext, gnbuf);
            float* t = gcur; gcur = gnext; gnext = t;
        } else {
            gather64_kernel<<<((size_t)n * 16 + 255) / 256, 256, 0, stream>>>(
                tb, (float*)d_out, startA, esrc, dinv, n);
        }
    }
}